// Round 9
// baseline (247.773 us; speedup 1.0000x reference)
//
#include <hip/hip_runtime.h>

// GCN 2-layer forward for MI355X.
// out = D^-1/2 (A+I) D^-1/2 (X W) + b, twice, relu between.
// g = (X W) * dinv ; tmp[c] = g[c] + sum_{e: col_e=c} g[row_e] ; out = tmp*dinv + b.
// R2: CSR gather. R3: parallel scan. R4: g stored bf16. R5: MFMA split-bf16 GEMM.
// R6: edge bucketing. R7/R8: consolidated CSR build (BCAP=6144 after overflow fix).
// R9: XCD-sliced gathers: feature-quarter q pinned to XCD pair via blockIdx&7
//     (measured round-robin mapping). Each XCD's L2 then holds a 3.2MB slice of
//     the gather table -> random reads become L2 hits. Perf-neutral if the
//     mapping assumption is wrong (correctness never depends on it).

constexpr int KD = 128;      // inner dim of both GEMMs (Fin = Fh = 128)
constexpr int CHUNK = 4096;  // edges per block in scatter pass
constexpr int BCAP = 6144;   // slack capacity per bucket (mean 4096, sigma ~64)

using short8  = __attribute__((ext_vector_type(8))) short;
using float4v = __attribute__((ext_vector_type(4))) float;

// ---------------- bf16 helpers (storage = ushort, math = fp32) ----------------

__device__ __forceinline__ unsigned short f2bf(float f) {
    unsigned int u = __float_as_uint(f);
    u = (u + 0x7fffu + ((u >> 16) & 1u)) >> 16;  // round-to-nearest-even
    return (unsigned short)u;
}

__device__ __forceinline__ float2 bfpair(unsigned int u) {
    float2 f;
    f.x = __uint_as_float(u << 16);          // low short = first feature
    f.y = __uint_as_float(u & 0xffff0000u);  // high short = second feature
    return f;
}

// split x = hi + lo (both bf16); subtraction is exact, |err| ~ 2^-17 |x|
__device__ __forceinline__ void bfsplit(float x, unsigned short& h, unsigned short& l) {
    h = f2bf(x);
    float fh = __uint_as_float((unsigned int)h << 16);
    l = f2bf(x - fh);
}

// ---------------- setup: W transpose+split (both layers) + gcur init ----------
__global__ __launch_bounds__(128) void setup(const float* __restrict__ W1,
                                             unsigned short* __restrict__ Wth1,
                                             unsigned short* __restrict__ Wtl1,
                                             const float* __restrict__ W2,
                                             unsigned short* __restrict__ Wth2,
                                             unsigned short* __restrict__ Wtl2,
                                             int* __restrict__ gcur) {
    int b = blockIdx.x;
    int n = threadIdx.x;
    int k = b & 127;
    if (b == 0) {
        gcur[n] = n * BCAP;
        gcur[n + 128] = (n + 128) * BCAP;
    }
    if (b < 128) {
        float w = W1[k * 128 + n];
        unsigned short h, l;
        bfsplit(w, h, l);
        Wth1[n * KD + k] = h;
        Wtl1[n * KD + k] = l;
    } else if (n < 64) {
        float w = W2[k * 64 + n];
        unsigned short h, l;
        bfsplit(w, h, l);
        Wth2[n * KD + k] = h;
        Wtl2[n * KD + k] = l;
    }
}

// ---------------- CSR build ----------------

// Edge scatter into slack buckets: per-block LDS hist -> one global cursor bump
// per (block,bucket) -> locally-ordered writes.
__global__ __launch_bounds__(256) void bucket_scatter(const int* __restrict__ row,
                                                      const int* __restrict__ col,
                                                      int* gcur,
                                                      int* __restrict__ bcol,
                                                      int* __restrict__ brow, int E) {
    __shared__ int lh[256];
    __shared__ int lbase[256];
    lh[threadIdx.x] = 0;
    __syncthreads();
    int base = blockIdx.x * CHUNK;
#pragma unroll
    for (int r = 0; r < CHUNK / 256; ++r) {
        int e = base + r * 256 + threadIdx.x;
        if (e < E) atomicAdd(&lh[col[e] >> 8], 1);
    }
    __syncthreads();
    int c0 = lh[threadIdx.x];
    lbase[threadIdx.x] = c0 ? atomicAdd(&gcur[threadIdx.x], c0) : 0;
    __syncthreads();
    lh[threadIdx.x] = 0;  // reuse as local running offset
    __syncthreads();
#pragma unroll
    for (int r = 0; r < CHUNK / 256; ++r) {
        int e = base + r * 256 + threadIdx.x;
        if (e < E) {
            int c = col[e];
            int b = c >> 8;
            int slot = lbase[b] + atomicAdd(&lh[b], 1);
            bcol[slot] = c;
            brow[slot] = row[e];
        }
    }
}

// 1 block: bucket counts (gcur[b]-b*BCAP) -> exclusive scan -> bstart; rowptr[N]=E.
__global__ __launch_bounds__(256) void bucket_scan(const int* __restrict__ gcur,
                                                   int* __restrict__ bstart,
                                                   int* rowptr, int N, int E) {
    __shared__ int s[256];
    int v = gcur[threadIdx.x] - threadIdx.x * BCAP;
    s[threadIdx.x] = v;
    __syncthreads();
    for (int off = 1; off < 256; off <<= 1) {
        int t = (threadIdx.x >= off) ? s[threadIdx.x - off] : 0;
        __syncthreads();
        s[threadIdx.x] += t;
        __syncthreads();
    }
    bstart[threadIdx.x] = s[threadIdx.x] - v;  // exclusive
    if (threadIdx.x == 0) rowptr[N] = E;
}

// One block per bucket: LDS hist of 256 nodes -> LDS scan -> rowptr/dinv/srow.
// Bucket-major + node-within-bucket order IS global CSR order.
__global__ __launch_bounds__(256) void bucket_csr(const int* __restrict__ bcol,
                                                  const int* __restrict__ brow,
                                                  const int* __restrict__ gcur,
                                                  const int* __restrict__ bstart,
                                                  int* __restrict__ rowptr,
                                                  float* __restrict__ dinv,
                                                  int* __restrict__ srow, int N) {
    __shared__ int lh[256];
    __shared__ int s[256];
    __shared__ int lcur[256];
    int b = blockIdx.x;
    int nE = gcur[b] - b * BCAP;
    int base = b * BCAP;
    lh[threadIdx.x] = 0;
    __syncthreads();
    for (int i = threadIdx.x; i < nE; i += 256)
        atomicAdd(&lh[bcol[base + i] & 255], 1);
    __syncthreads();
    int v = lh[threadIdx.x];
    s[threadIdx.x] = v;
    __syncthreads();
    for (int off = 1; off < 256; off <<= 1) {
        int t = (threadIdx.x >= off) ? s[threadIdx.x - off] : 0;
        __syncthreads();
        s[threadIdx.x] += t;
        __syncthreads();
    }
    int myStart = bstart[b] + s[threadIdx.x] - v;  // exclusive
    int node = (b << 8) + threadIdx.x;
    if (node < N) {
        rowptr[node] = myStart;
        dinv[node] = rsqrtf(1.0f + (float)v);
    }
    lcur[threadIdx.x] = myStart;
    __syncthreads();
    for (int i = threadIdx.x; i < nE; i += 256) {
        int c = bcol[base + i] & 255;
        int slot = atomicAdd(&lcur[c], 1);
        srow[slot] = brow[base + i];
    }
}

// ---------------- MFMA GEMM: G[n,:] = bf16( dinv[n] * (X[n,:] @ W) ) ----------
// One wave per 16-row tile. A-frags built in registers from fp32 X (hi/lo split);
// B-frags from Wt_hi/Wt_lo (L2-resident). acc = AhBh + AlBh + AhBl.
template <int FOUT>
__global__ __launch_bounds__(256) void gemm_mfma(const float* __restrict__ X,
                                                 const unsigned short* __restrict__ Wth,
                                                 const unsigned short* __restrict__ Wtl,
                                                 const float* __restrict__ dinv,
                                                 unsigned short* __restrict__ G, int N) {
    constexpr int NT = FOUT / 16;  // col tiles
    int wave = threadIdx.x >> 6;
    int lane = threadIdx.x & 63;
    int row0 = (blockIdx.x * 4 + wave) * 16;
    if (row0 >= N) return;
    int m = lane & 15;
    int quad = lane >> 4;

    float4v acc[NT];
#pragma unroll
    for (int ct = 0; ct < NT; ++ct) acc[ct] = (float4v){0.f, 0.f, 0.f, 0.f};

    const float* xrow = X + (size_t)(row0 + m) * KD + quad * 8;

#pragma unroll
    for (int ks = 0; ks < 4; ++ks) {
        float4 xa = *(const float4*)(xrow + ks * 32);
        float4 xb = *(const float4*)(xrow + ks * 32 + 4);
        float xs[8] = {xa.x, xa.y, xa.z, xa.w, xb.x, xb.y, xb.z, xb.w};
        short8 ah, al;
#pragma unroll
        for (int j = 0; j < 8; ++j) {
            unsigned short h, l;
            bfsplit(xs[j], h, l);
            ah[j] = (short)h;
            al[j] = (short)l;
        }
        int koff = ks * 32 + quad * 8;
#pragma unroll
        for (int ct = 0; ct < NT; ++ct) {
            const unsigned short* wb = Wth + (size_t)(ct * 16 + m) * KD + koff;
            const unsigned short* wl = Wtl + (size_t)(ct * 16 + m) * KD + koff;
            short8 bh = *(const short8*)wb;
            short8 bl = *(const short8*)wl;
            acc[ct] = __builtin_amdgcn_mfma_f32_16x16x32_bf16(ah, bh, acc[ct], 0, 0, 0);
            acc[ct] = __builtin_amdgcn_mfma_f32_16x16x32_bf16(al, bh, acc[ct], 0, 0, 0);
            acc[ct] = __builtin_amdgcn_mfma_f32_16x16x32_bf16(ah, bl, acc[ct], 0, 0, 0);
        }
    }

    // epilogue: row = row0 + quad*4 + r, col = ct*16 + m
#pragma unroll
    for (int r = 0; r < 4; ++r) {
        int row = row0 + quad * 4 + r;
        float s = dinv[row];
#pragma unroll
        for (int ct = 0; ct < NT; ++ct) {
            G[(size_t)row * FOUT + ct * 16 + m] = f2bf(acc[ct][r] * s);
        }
    }
}

// ---------------- XCD-sliced CSR gather + finalize, bf16 operand -------------
// F=128: 16-lane group per (node, quarter). quarter q = (blockIdx&7)>>1 pins a
// 3.2MB table slice to one XCD pair's L2 (round-robin block->XCD dispatch).
template <bool RELU>
__global__ __launch_bounds__(256) void gather128x(const int* __restrict__ rowptr,
                                                  const int* __restrict__ srow,
                                                  const unsigned int* __restrict__ G,  // bf16x2
                                                  const float* __restrict__ dinv,
                                                  const float* __restrict__ bias,
                                                  float* __restrict__ O, int N) {
    int b7 = blockIdx.x & 7;
    int q = b7 >> 1;           // feature quarter 0..3
    int sub = b7 & 1;
    int gb = blockIdx.x >> 3;
    int g = threadIdx.x >> 4;  // 16-lane group 0..15
    int l = threadIdx.x & 15;
    int node = (gb * 2 + sub) * 16 + g;
    if (node >= N) return;
    int qoff = q * 16 + l;     // dword index within 64-dword row

    int beg = rowptr[node];
    int end = rowptr[node + 1];

    float2 s0 = bfpair(G[(size_t)node * 64 + qoff]);  // self-loop
    float ax = s0.x, ay = s0.y;

    int e = beg;
    for (; e + 3 < end; e += 4) {
        int r0 = srow[e], r1 = srow[e + 1], r2 = srow[e + 2], r3 = srow[e + 3];
        float2 v0 = bfpair(G[(size_t)r0 * 64 + qoff]);
        float2 v1 = bfpair(G[(size_t)r1 * 64 + qoff]);
        float2 v2 = bfpair(G[(size_t)r2 * 64 + qoff]);
        float2 v3 = bfpair(G[(size_t)r3 * 64 + qoff]);
        ax += (v0.x + v1.x) + (v2.x + v3.x);
        ay += (v0.y + v1.y) + (v2.y + v3.y);
    }
    for (; e < end; ++e) {
        float2 v = bfpair(G[(size_t)srow[e] * 64 + qoff]);
        ax += v.x;
        ay += v.y;
    }
    float s = dinv[node];
    float2 bv = ((const float2*)bias)[qoff];
    float ox = ax * s + bv.x;
    float oy = ay * s + bv.y;
    if (RELU) { ox = fmaxf(ox, 0.f); oy = fmaxf(oy, 0.f); }
    ((float2*)O)[(size_t)node * 64 + qoff] = make_float2(ox, oy);
}

// F=64: 16-lane group per (node, half). half h = (blockIdx&7)>>2 -> 3.2MB slice
// per 4-XCD set.
template <bool RELU>
__global__ __launch_bounds__(256) void gather64x(const int* __restrict__ rowptr,
                                                 const int* __restrict__ srow,
                                                 const unsigned int* __restrict__ G,  // bf16x2
                                                 const float* __restrict__ dinv,
                                                 const float* __restrict__ bias,
                                                 float* __restrict__ O, int N) {
    int b7 = blockIdx.x & 7;
    int h = b7 >> 2;           // feature half 0..1
    int sub = b7 & 3;
    int gb = blockIdx.x >> 3;
    int g = threadIdx.x >> 4;
    int l = threadIdx.x & 15;
    int node = (gb * 4 + sub) * 16 + g;
    if (node >= N) return;
    int hoff = h * 16 + l;     // dword index within 32-dword row

    int beg = rowptr[node];
    int end = rowptr[node + 1];

    float2 s0 = bfpair(G[(size_t)node * 32 + hoff]);  // self-loop
    float ax = s0.x, ay = s0.y;

    int e = beg;
    for (; e + 3 < end; e += 4) {
        int r0 = srow[e], r1 = srow[e + 1], r2 = srow[e + 2], r3 = srow[e + 3];
        float2 v0 = bfpair(G[(size_t)r0 * 32 + hoff]);
        float2 v1 = bfpair(G[(size_t)r1 * 32 + hoff]);
        float2 v2 = bfpair(G[(size_t)r2 * 32 + hoff]);
        float2 v3 = bfpair(G[(size_t)r3 * 32 + hoff]);
        ax += (v0.x + v1.x) + (v2.x + v3.x);
        ay += (v0.y + v1.y) + (v2.y + v3.y);
    }
    for (; e < end; ++e) {
        float2 v = bfpair(G[(size_t)srow[e] * 32 + hoff]);
        ax += v.x;
        ay += v.y;
    }
    float s = dinv[node];
    float2 bv = ((const float2*)bias)[hoff];
    float ox = ax * s + bv.x;
    float oy = ay * s + bv.y;
    if (RELU) { ox = fmaxf(ox, 0.f); oy = fmaxf(oy, 0.f); }
    ((float2*)O)[(size_t)node * 32 + hoff] = make_float2(ox, oy);
}

extern "C" void kernel_launch(void* const* d_in, const int* in_sizes, int n_in,
                              void* d_out, int out_size, void* d_ws, size_t ws_size,
                              hipStream_t stream) {
    const float* x  = (const float*)d_in[0];
    const int*   ei = (const int*)d_in[1];   // int32
    const float* W1 = (const float*)d_in[2];
    const float* b1 = (const float*)d_in[3];
    const float* W2 = (const float*)d_in[4];
    const float* b2 = (const float*)d_in[5];
    float* out = (float*)d_out;

    int N = in_sizes[0] / 128;
    int E = in_sizes[1] / 2;
    const int* row = ei;       // edge_index[0]
    const int* col = ei + E;   // edge_index[1]

    // Workspace layout (all regions written before read each call)
    char* ws = (char*)d_ws;
    float* dinv   = (float*)(ws + 0x000000);             // 200 KB
    int*   rowptr = (int*)  (ws + 0x080000);             // 200 KB + 4
    int*   gcur   = (int*)  (ws + 0x0F9000);             // 1 KB
    int*   bstart = (int*)  (ws + 0x0FA000);             // 1 KB
    int*   srow   = (int*)  (ws + 0x100000);             // 3.2 MB
    unsigned short* g1 = (unsigned short*)(ws + 0x440000);     // 12.8 MB
    unsigned short* wth1 = (unsigned short*)(ws + 0x10C0000);  // 32 KB
    unsigned short* wtl1 = (unsigned short*)(ws + 0x10D0000);  // 32 KB
    unsigned short* wth2 = (unsigned short*)(ws + 0x10E0000);  // 16 KB
    unsigned short* wtl2 = (unsigned short*)(ws + 0x10F0000);  // 16 KB
    float* h2     = (float*)(ws + 0x1200000);            // 25.6 MB
    unsigned short* g2 = (unsigned short*)(ws + 0x2C00000);    // 6.4 MB
    // Slack bucket buffers (256 x BCAP ints = 6.29 MB each) overlap h2's region:
    // consumed by bucket_csr before gather128x first writes h2.
    int*   bcol   = (int*)  (ws + 0x1200000);            // 6.29 MB
    int*   brow   = (int*)  (ws + 0x1800000);            // 6.29 MB (ends 0x1E00000)

    int NB_BKT  = (E + CHUNK - 1) / CHUNK;
    int NBUCKET = (N + 255) / 256;   // 196

    // ---- setup + CSR build ----
    setup<<<256, 128, 0, stream>>>(W1, wth1, wtl1, W2, wth2, wtl2, gcur);
    bucket_scatter<<<NB_BKT, 256, 0, stream>>>(row, col, gcur, bcol, brow, E);
    bucket_scan<<<1, 256, 0, stream>>>(gcur, bstart, rowptr, N, E);
    bucket_csr<<<NBUCKET, 256, 0, stream>>>(bcol, brow, gcur, bstart, rowptr, dinv, srow, N);

    int nb;
    // ---- layer 1 (F=128, relu) ----
    nb = (N + 63) / 64;  // 4 waves/block, 16 rows/wave
    gemm_mfma<128><<<nb, 256, 0, stream>>>(x, wth1, wtl1, dinv, g1, N);
    nb = ((N + 31) / 32) * 8;  // XCD-sliced: 8 block-variants (4 quarters x 2 sub)
    gather128x<true><<<nb, 256, 0, stream>>>(rowptr, srow, (const unsigned int*)g1,
                                             dinv, b1, h2, N);

    // ---- layer 2 (F=64, no relu) ----
    nb = (N + 63) / 64;
    gemm_mfma<64><<<nb, 256, 0, stream>>>(h2, wth2, wtl2, dinv, g2, N);
    nb = ((N + 63) / 64) * 8;  // XCD-sliced: 8 block-variants (2 halves x 4 sub)
    gather64x<false><<<nb, 256, 0, stream>>>(rowptr, srow, (const unsigned int*)g2,
                                             dinv, b2, out, N);
}

// Round 10
// 229.159 us; speedup vs baseline: 1.0812x; 1.0812x over previous
//
#include <hip/hip_runtime.h>

// GCN 2-layer forward for MI355X.
// out = D^-1/2 (A+I) D^-1/2 (X W) + b, twice, relu between.
// g = (X W) * dinv ; tmp[c] = g[c] + sum_{e: col_e=c} g[row_e] ; out = tmp*dinv + b.
// R2: CSR gather. R3: parallel scan. R4: g stored bf16. R5: MFMA split-bf16 GEMM.
// R6: edge bucketing. R7/R8: consolidated CSR build (BCAP=6144).
// R9: XCD-sliced gather FAILED (FETCH unchanged, divergence cost) -> reverted.
// R10: wave-uniform scalar addressing in gather128 (readfirstlane on srow),
//      unroll 8; packed (row<<16|col) edge records + ushort srow; bucket_scan
//      folded into bucket_csr. 7 launches.

constexpr int KD = 128;      // inner dim of both GEMMs (Fin = Fh = 128)
constexpr int CHUNK = 4096;  // edges per block in scatter pass
constexpr int BCAP = 6144;   // slack capacity per bucket (mean 4096, sigma ~64)

using short8  = __attribute__((ext_vector_type(8))) short;
using float4v = __attribute__((ext_vector_type(4))) float;

// ---------------- bf16 helpers (storage = ushort, math = fp32) ----------------

__device__ __forceinline__ unsigned short f2bf(float f) {
    unsigned int u = __float_as_uint(f);
    u = (u + 0x7fffu + ((u >> 16) & 1u)) >> 16;  // round-to-nearest-even
    return (unsigned short)u;
}

__device__ __forceinline__ float2 bfpair(unsigned int u) {
    float2 f;
    f.x = __uint_as_float(u << 16);          // low short = first feature
    f.y = __uint_as_float(u & 0xffff0000u);  // high short = second feature
    return f;
}

// split x = hi + lo (both bf16); subtraction is exact, |err| ~ 2^-17 |x|
__device__ __forceinline__ void bfsplit(float x, unsigned short& h, unsigned short& l) {
    h = f2bf(x);
    float fh = __uint_as_float((unsigned int)h << 16);
    l = f2bf(x - fh);
}

// ---------------- setup: W transpose+split (both layers) + gcur init ----------
__global__ __launch_bounds__(128) void setup(const float* __restrict__ W1,
                                             unsigned short* __restrict__ Wth1,
                                             unsigned short* __restrict__ Wtl1,
                                             const float* __restrict__ W2,
                                             unsigned short* __restrict__ Wth2,
                                             unsigned short* __restrict__ Wtl2,
                                             int* __restrict__ gcur) {
    int b = blockIdx.x;
    int n = threadIdx.x;
    int k = b & 127;
    if (b == 0) {
        gcur[n] = n * BCAP;
        gcur[n + 128] = (n + 128) * BCAP;
    }
    if (b < 128) {
        float w = W1[k * 128 + n];
        unsigned short h, l;
        bfsplit(w, h, l);
        Wth1[n * KD + k] = h;
        Wtl1[n * KD + k] = l;
    } else if (n < 64) {
        float w = W2[k * 64 + n];
        unsigned short h, l;
        bfsplit(w, h, l);
        Wth2[n * KD + k] = h;
        Wtl2[n * KD + k] = l;
    }
}

// ---------------- CSR build ----------------

// Edge scatter into slack buckets (by col>>8). Packed record: (row<<16)|col
// (both < 50000 < 2^16). Per-block LDS hist -> one cursor bump per bucket.
__global__ __launch_bounds__(256) void bucket_scatter(const int* __restrict__ row,
                                                      const int* __restrict__ col,
                                                      int* gcur,
                                                      unsigned int* __restrict__ bpack,
                                                      int E) {
    __shared__ int lh[256];
    __shared__ int lbase[256];
    lh[threadIdx.x] = 0;
    __syncthreads();
    int base = blockIdx.x * CHUNK;
#pragma unroll
    for (int r = 0; r < CHUNK / 256; ++r) {
        int e = base + r * 256 + threadIdx.x;
        if (e < E) atomicAdd(&lh[col[e] >> 8], 1);
    }
    __syncthreads();
    int c0 = lh[threadIdx.x];
    lbase[threadIdx.x] = c0 ? atomicAdd(&gcur[threadIdx.x], c0) : 0;
    __syncthreads();
    lh[threadIdx.x] = 0;  // reuse as local running offset
    __syncthreads();
#pragma unroll
    for (int r = 0; r < CHUNK / 256; ++r) {
        int e = base + r * 256 + threadIdx.x;
        if (e < E) {
            int c = col[e];
            int b = c >> 8;
            int slot = lbase[b] + atomicAdd(&lh[b], 1);
            bpack[slot] = ((unsigned int)row[e] << 16) | (unsigned int)c;
        }
    }
}

// One block per bucket. Recomputes the 256-wide bucket-count scan in LDS
// (replaces the separate bucket_scan launch), then LDS node hist -> scan ->
// rowptr/dinv/srow. Bucket-major + node-within-bucket order IS CSR order.
__global__ __launch_bounds__(256) void bucket_csr(const unsigned int* __restrict__ bpack,
                                                  const int* __restrict__ gcur,
                                                  int* __restrict__ rowptr,
                                                  float* __restrict__ dinv,
                                                  unsigned short* __restrict__ srow,
                                                  int N, int E) {
    __shared__ int s[256];
    __shared__ int lh[256];
    __shared__ int lcur[256];
    __shared__ int sh_bstart;
    int b = blockIdx.x;
    int t = threadIdx.x;
    int cntb = gcur[t] - t * BCAP;
    s[t] = cntb;
    __syncthreads();
    for (int off = 1; off < 256; off <<= 1) {
        int tv = (t >= off) ? s[t - off] : 0;
        __syncthreads();
        s[t] += tv;
        __syncthreads();
    }
    if (t == b) sh_bstart = s[t] - cntb;  // exclusive prefix of this bucket
    if (b == 0 && t == 0) rowptr[N] = E;
    lh[t] = 0;
    __syncthreads();
    int bstart = sh_bstart;
    int nE = gcur[b] - b * BCAP;
    int base = b * BCAP;
    for (int i = t; i < nE; i += 256)
        atomicAdd(&lh[bpack[base + i] & 255], 1);
    __syncthreads();
    int v = lh[t];
    s[t] = v;
    __syncthreads();
    for (int off = 1; off < 256; off <<= 1) {
        int tv = (t >= off) ? s[t - off] : 0;
        __syncthreads();
        s[t] += tv;
        __syncthreads();
    }
    int myStart = bstart + s[t] - v;  // exclusive
    int node = (b << 8) + t;
    if (node < N) {
        rowptr[node] = myStart;
        dinv[node] = rsqrtf(1.0f + (float)v);
    }
    lcur[t] = myStart;
    __syncthreads();
    for (int i = t; i < nE; i += 256) {
        unsigned int p = bpack[base + i];
        int slot = atomicAdd(&lcur[p & 255], 1);
        srow[slot] = (unsigned short)(p >> 16);
    }
}

// ---------------- MFMA GEMM: G[n,:] = bf16( dinv[n] * (X[n,:] @ W) ) ----------
// One wave per 16-row tile. A-frags built in registers from fp32 X (hi/lo split);
// B-frags from Wt_hi/Wt_lo (L2-resident). acc = AhBh + AlBh + AhBl.
template <int FOUT>
__global__ __launch_bounds__(256) void gemm_mfma(const float* __restrict__ X,
                                                 const unsigned short* __restrict__ Wth,
                                                 const unsigned short* __restrict__ Wtl,
                                                 const float* __restrict__ dinv,
                                                 unsigned short* __restrict__ G, int N) {
    constexpr int NT = FOUT / 16;  // col tiles
    int wave = threadIdx.x >> 6;
    int lane = threadIdx.x & 63;
    int row0 = (blockIdx.x * 4 + wave) * 16;
    if (row0 >= N) return;
    int m = lane & 15;
    int quad = lane >> 4;

    float4v acc[NT];
#pragma unroll
    for (int ct = 0; ct < NT; ++ct) acc[ct] = (float4v){0.f, 0.f, 0.f, 0.f};

    const float* xrow = X + (size_t)(row0 + m) * KD + quad * 8;

#pragma unroll
    for (int ks = 0; ks < 4; ++ks) {
        float4 xa = *(const float4*)(xrow + ks * 32);
        float4 xb = *(const float4*)(xrow + ks * 32 + 4);
        float xs[8] = {xa.x, xa.y, xa.z, xa.w, xb.x, xb.y, xb.z, xb.w};
        short8 ah, al;
#pragma unroll
        for (int j = 0; j < 8; ++j) {
            unsigned short h, l;
            bfsplit(xs[j], h, l);
            ah[j] = (short)h;
            al[j] = (short)l;
        }
        int koff = ks * 32 + quad * 8;
#pragma unroll
        for (int ct = 0; ct < NT; ++ct) {
            const unsigned short* wb = Wth + (size_t)(ct * 16 + m) * KD + koff;
            const unsigned short* wl = Wtl + (size_t)(ct * 16 + m) * KD + koff;
            short8 bh = *(const short8*)wb;
            short8 bl = *(const short8*)wl;
            acc[ct] = __builtin_amdgcn_mfma_f32_16x16x32_bf16(ah, bh, acc[ct], 0, 0, 0);
            acc[ct] = __builtin_amdgcn_mfma_f32_16x16x32_bf16(al, bh, acc[ct], 0, 0, 0);
            acc[ct] = __builtin_amdgcn_mfma_f32_16x16x32_bf16(ah, bl, acc[ct], 0, 0, 0);
        }
    }

    // epilogue: row = row0 + quad*4 + r, col = ct*16 + m
#pragma unroll
    for (int r = 0; r < 4; ++r) {
        int row = row0 + quad * 4 + r;
        float s = dinv[row];
#pragma unroll
        for (int ct = 0; ct < NT; ++ct) {
            G[(size_t)row * FOUT + ct * 16 + m] = f2bf(acc[ct][r] * s);
        }
    }
}

// ---------------- CSR gather + finalize (fused), bf16 operand ----------------
// F=128: one wave per node. srow is wave-uniform -> readfirstlane gives scalar
// row base (saddr-form loads, minimal VALU per edge). Unroll 8 for MLP.
template <bool RELU>
__global__ __launch_bounds__(256) void gather128(const int* __restrict__ rowptr,
                                                 const unsigned short* __restrict__ srow,
                                                 const unsigned int* __restrict__ G,  // bf16x2
                                                 const float* __restrict__ dinv,
                                                 const float* __restrict__ bias,
                                                 float* __restrict__ O, int N) {
    int node = (blockIdx.x * 256 + threadIdx.x) >> 6;
    int lane = threadIdx.x & 63;
    if (node >= N) return;
    int beg = rowptr[node];
    int end = rowptr[node + 1];

    float ax, ay;
    {
        float2 s0 = bfpair(G[(size_t)node * 64 + lane]);  // self-loop
        ax = s0.x; ay = s0.y;
    }

    int e = beg;
    for (; e + 7 < end; e += 8) {
        unsigned int u[8];
#pragma unroll
        for (int j = 0; j < 8; ++j) {
            int r = __builtin_amdgcn_readfirstlane((int)srow[e + j]);
            const unsigned int* p = G + (size_t)r * 64;  // uniform base (SGPR)
            u[j] = p[lane];
        }
        float sx = 0.f, sy = 0.f;
#pragma unroll
        for (int j = 0; j < 8; ++j) {
            float2 v = bfpair(u[j]);
            sx += v.x; sy += v.y;
        }
        ax += sx; ay += sy;
    }
    for (; e < end; ++e) {
        int r = __builtin_amdgcn_readfirstlane((int)srow[e]);
        const unsigned int* p = G + (size_t)r * 64;
        float2 v = bfpair(p[lane]);
        ax += v.x; ay += v.y;
    }
    float s = dinv[node];
    float2 bv = ((const float2*)bias)[lane];
    float ox = ax * s + bv.x;
    float oy = ay * s + bv.y;
    if (RELU) { ox = fmaxf(ox, 0.f); oy = fmaxf(oy, 0.f); }
    ((float2*)O)[(size_t)node * 64 + lane] = make_float2(ox, oy);
}

// F=64: half-wave per node (32 lanes x bf16x2 = 128B row), 2 nodes per wave.
// srow NOT wave-uniform here (two nodes share the wave) -> no readfirstlane.
template <bool RELU>
__global__ __launch_bounds__(256) void gather64(const int* __restrict__ rowptr,
                                                const unsigned short* __restrict__ srow,
                                                const unsigned int* __restrict__ G,  // bf16x2
                                                const float* __restrict__ dinv,
                                                const float* __restrict__ bias,
                                                float* __restrict__ O, int N) {
    int tid = blockIdx.x * 256 + threadIdx.x;
    int node = tid >> 5;          // half-wave per node
    int lane = threadIdx.x & 31;
    if (node >= N) return;
    int beg = rowptr[node];
    int end = rowptr[node + 1];

    float2 s0 = bfpair(G[(size_t)node * 32 + lane]);  // self-loop
    float ax = s0.x, ay = s0.y;

    int e = beg;
    for (; e + 7 < end; e += 8) {
        unsigned int u[8];
#pragma unroll
        for (int j = 0; j < 8; ++j) {
            int r = (int)srow[e + j];
            u[j] = G[(size_t)r * 32 + lane];
        }
        float sx = 0.f, sy = 0.f;
#pragma unroll
        for (int j = 0; j < 8; ++j) {
            float2 v = bfpair(u[j]);
            sx += v.x; sy += v.y;
        }
        ax += sx; ay += sy;
    }
    for (; e < end; ++e) {
        float2 v = bfpair(G[(size_t)srow[e] * 32 + lane]);
        ax += v.x;
        ay += v.y;
    }
    float s = dinv[node];
    float2 bv = ((const float2*)bias)[lane];
    float ox = ax * s + bv.x;
    float oy = ay * s + bv.y;
    if (RELU) { ox = fmaxf(ox, 0.f); oy = fmaxf(oy, 0.f); }
    ((float2*)O)[(size_t)node * 32 + lane] = make_float2(ox, oy);
}

extern "C" void kernel_launch(void* const* d_in, const int* in_sizes, int n_in,
                              void* d_out, int out_size, void* d_ws, size_t ws_size,
                              hipStream_t stream) {
    const float* x  = (const float*)d_in[0];
    const int*   ei = (const int*)d_in[1];   // int32
    const float* W1 = (const float*)d_in[2];
    const float* b1 = (const float*)d_in[3];
    const float* W2 = (const float*)d_in[4];
    const float* b2 = (const float*)d_in[5];
    float* out = (float*)d_out;

    int N = in_sizes[0] / 128;
    int E = in_sizes[1] / 2;
    const int* row = ei;       // edge_index[0]
    const int* col = ei + E;   // edge_index[1]

    // Workspace layout (all regions written before read each call)
    char* ws = (char*)d_ws;
    float* dinv   = (float*)(ws + 0x000000);             // 200 KB
    int*   rowptr = (int*)  (ws + 0x080000);             // 200 KB + 4
    int*   gcur   = (int*)  (ws + 0x0F9000);             // 1 KB
    unsigned short* srow = (unsigned short*)(ws + 0x100000);   // 1.6 MB
    unsigned short* g1 = (unsigned short*)(ws + 0x440000);     // 12.8 MB
    unsigned short* wth1 = (unsigned short*)(ws + 0x10C0000);  // 32 KB
    unsigned short* wtl1 = (unsigned short*)(ws + 0x10D0000);  // 32 KB
    unsigned short* wth2 = (unsigned short*)(ws + 0x10E0000);  // 16 KB
    unsigned short* wtl2 = (unsigned short*)(ws + 0x10F0000);  // 16 KB
    float* h2     = (float*)(ws + 0x1200000);            // 25.6 MB
    unsigned short* g2 = (unsigned short*)(ws + 0x2C00000);    // 6.4 MB
    // Packed slack bucket buffer (256 x BCAP uints = 6.29 MB) overlaps h2's
    // region: consumed by bucket_csr before gather128 first writes h2.
    unsigned int* bpack = (unsigned int*)(ws + 0x1200000);     // 6.29 MB

    int NB_BKT  = (E + CHUNK - 1) / CHUNK;
    int NBUCKET = (N + 255) / 256;   // 196

    // ---- setup + CSR build (3 launches) ----
    setup<<<256, 128, 0, stream>>>(W1, wth1, wtl1, W2, wth2, wtl2, gcur);
    bucket_scatter<<<NB_BKT, 256, 0, stream>>>(row, col, gcur, bpack, E);
    bucket_csr<<<NBUCKET, 256, 0, stream>>>(bpack, gcur, rowptr, dinv, srow, N, E);

    int nb;
    // ---- layer 1 (F=128, relu) ----
    nb = (N + 63) / 64;  // 4 waves/block, 16 rows/wave
    gemm_mfma<128><<<nb, 256, 0, stream>>>(x, wth1, wtl1, dinv, g1, N);
    nb = (N + 3) / 4;    // one wave per node
    gather128<true><<<nb, 256, 0, stream>>>(rowptr, srow, (const unsigned int*)g1,
                                            dinv, b1, h2, N);

    // ---- layer 2 (F=64, no relu) ----
    nb = (N + 63) / 64;
    gemm_mfma<64><<<nb, 256, 0, stream>>>(h2, wth2, wtl2, dinv, g2, N);
    nb = (N + 7) / 8;    // half-wave per node
    gather64<false><<<nb, 256, 0, stream>>>(rowptr, srow, (const unsigned int*)g2,
                                            dinv, b2, out, N);
}